// Round 7
// baseline (1361.933 us; speedup 1.0000x reference)
//
#include <hip/hip_runtime.h>
#include <hip/hip_bf16.h>
#include <cstdint>

// PhaseEncodingSNN: B=64, T=512, I=256, H=512, O=256.
// R11 scan changes (on top of R10's validated base):
//  - barrier WITHOUT vmcnt drain: `s_waitcnt lgkmcnt(0); s_barrier`. With the
//    full P array (no ring reuse) the per-step vmcnt(0) drain has no
//    correctness role (cross-lane data is LDS-only; P/rp are consumed by
//    other agents via polling; no address rewritten). Removes the producer's
//    ~400-600cy LLC store-ack wait from every step. (R9's failure was the
//    asm-poll register hazard, NOT this barrier.)
//  - depth-2 pipelined poll via C-level renaming (cur=nx1; nx1=load): check
//    waits on a load issued one iteration earlier -> detect ~1.25L vs 1.5L.
//    All loads compiler-managed (R9 lesson: no inline-asm on the data path).
//  - one-time vmcnt(0) before kernel end (completion visibility hedge).
//  - 3 weight-split launches merged into one k_split3w (-2 launch gaps).
// Everything else bitwise == R10 (qword exchange, fused x-split GEMM1,
// fmaf order, swizzle reduce, LIF, store order).

#define T_STEPS 512
#define BATCH 64
#define HID 512
#define IN_DIM 256
#define OUT_DIM 256
#define BETA 0.9f
#define THR 1.0f
#define SENT 0x7FC00000u

typedef __attribute__((ext_vector_type(8))) short short8;
typedef __attribute__((ext_vector_type(4))) float float4v;
typedef unsigned short ushort_t;
typedef unsigned long long u64_t;

// ---------------------------------------------------------------- NaN fill
__global__ __launch_bounds__(256) void k_fill_nan(uint32_t* __restrict__ P) {
  const int idx = blockIdx.x * 256 + threadIdx.x;  // 65536 threads
  uint4 s = make_uint4(SENT, SENT, SENT, SENT);
  uint4* p4 = (uint4*)P;
  for (int i = idx; i < (32768 * 512) / 4; i += 65536) p4[i] = s;
}

// ---------------------------------------------------------------- fp32 -> hi/lo bf16 split
__device__ __forceinline__ void split1(float v, ushort_t* hi, ushort_t* lo) {
  uint32_t u = __float_as_uint(v);
  uint32_t rh = u + 0x7FFFu + ((u >> 16) & 1u);   // RNE to bf16
  ushort_t h = (ushort_t)(rh >> 16);
  float hf = __uint_as_float(((uint32_t)h) << 16);
  float l = v - hf;
  uint32_t ul = __float_as_uint(l);
  uint32_t rl = ul + 0x7FFFu + ((ul >> 16) & 1u);
  *hi = h;
  *lo = (ushort_t)(rl >> 16);
}

// merged weight splits: [0,131072) W_in, [131072,393216) W_ih,
// [393216,524288) W_out.  524288 elems / (512 blk * 256 thr) = 4 per thread.
__global__ __launch_bounds__(256) void k_split3w(
    const float* __restrict__ W_in, ushort_t* __restrict__ win_hi, ushort_t* __restrict__ win_lo,
    const float* __restrict__ W_ih, ushort_t* __restrict__ wih_hi, ushort_t* __restrict__ wih_lo,
    const float* __restrict__ W_out, ushort_t* __restrict__ wout_hi, ushort_t* __restrict__ wout_lo) {
  int i = blockIdx.x * 256 + threadIdx.x;
  for (; i < 524288; i += 131072) {
    const float* src; ushort_t* hi; ushort_t* lo; int off;
    if (i < 131072)      { src = W_in;  hi = win_hi;  lo = win_lo;  off = i; }
    else if (i < 393216) { src = W_ih;  hi = wih_hi;  lo = wih_lo;  off = i - 131072; }
    else                 { src = W_out; hi = wout_hi; lo = wout_lo; off = i - 393216; }
    split1(src[off], hi + off, lo + off);
  }
}

// split helpers (bitwise-identical math), 2 elems -> packed u32
__device__ __forceinline__ uint32_t rne_hi2(uint32_t ua, uint32_t ub) {
  uint32_t ra = ua + 0x7FFFu + ((ua >> 16) & 1u);
  uint32_t rb = ub + 0x7FFFu + ((ub >> 16) & 1u);
  return (ra >> 16) | (rb & 0xFFFF0000u);
}
__device__ __forceinline__ uint32_t rne_lo2(uint32_t ua, uint32_t ub) {
  uint32_t ra = ua + 0x7FFFu + ((ua >> 16) & 1u);
  uint32_t rb = ub + 0x7FFFu + ((ub >> 16) & 1u);
  float la = __uint_as_float(ua) - __uint_as_float(ra & 0xFFFF0000u);
  float lb = __uint_as_float(ub) - __uint_as_float(rb & 0xFFFF0000u);
  uint32_t ula = __float_as_uint(la), ulb = __float_as_uint(lb);
  uint32_t rla = ula + 0x7FFFu + ((ula >> 16) & 1u);
  uint32_t rlb = ulb + 0x7FFFu + ((ulb >> 16) & 1u);
  return (rla >> 16) | (rlb & 0xFFFF0000u);
}

// ---------------------------------------------------------------- softmax over t
__global__ __launch_bounds__(256) void k_softmax_t(
    const float* __restrict__ TA, float* __restrict__ attn) {
  __shared__ float redm[8][32];
  __shared__ float reds[8][32];
  const int ol = threadIdx.x & 31;
  const int tg = threadIdx.x >> 5;
  const int o = blockIdx.x * 32 + ol;
  float mx = -1e30f;
  for (int i = 0; i < 64; ++i) {
    float v = TA[(size_t)(tg * 64 + i) * OUT_DIM + o];
    mx = fmaxf(mx, v);
  }
  redm[tg][ol] = mx;
  __syncthreads();
  float m = redm[0][ol];
#pragma unroll
  for (int j = 1; j < 8; ++j) m = fmaxf(m, redm[j][ol]);
  float s = 0.f;
  for (int i = 0; i < 64; ++i) {
    float v = TA[(size_t)(tg * 64 + i) * OUT_DIM + o];
    s += __expf(v - m);
  }
  reds[tg][ol] = s;
  __syncthreads();
  float tot = 0.f;
#pragma unroll
  for (int j = 0; j < 8; ++j) tot += reds[j][ol];
  const float inv = 1.0f / tot;
  for (int i = 0; i < 64; ++i) {
    int t = tg * 64 + i;
    float v = TA[(size_t)t * OUT_DIM + o];
    attn[(size_t)t * OUT_DIM + o] = __expf(v - m) * inv;
  }
}

// ---------------------------------------------------------------- MFMA GEMM, fused-split A (x fp32), 3-term
__global__ __launch_bounds__(256) void k_gemm_fsplit3(
    const float* __restrict__ A, const ushort_t* __restrict__ Bhi,
    const ushort_t* __restrict__ Blo, const float* __restrict__ bias,
    float* __restrict__ C, int M, int N, int K) {
  __shared__ ushort_t At[2][128 * 40];
  __shared__ ushort_t Bt[2][128 * 40];
  const int tid = threadIdx.x;
  const int row0 = blockIdx.x * 128, col0 = blockIdx.y * 128;
  const int w = tid >> 6, lane = tid & 63;
  const int wm = (w >> 1) * 64, wn = (w & 1) * 64;
  const int l15 = lane & 15, quad = lane >> 4;
  float4v acc[4][4];
#pragma unroll
  for (int i = 0; i < 4; ++i)
#pragma unroll
    for (int j = 0; j < 4; ++j) acc[i][j] = (float4v){0.f, 0.f, 0.f, 0.f};

  for (int k0 = 0; k0 < K; k0 += 32) {
#pragma unroll
    for (int it = 0; it < 2; ++it) {
      int idx = it * 256 + tid;          // 0..511
      int r = idx >> 2;                  // row 0..127
      int c8 = (idx & 3) << 3;           // k-offset {0,8,16,24}
      const float* ap_ = &A[(size_t)(row0 + r) * K + k0 + c8];
      uint4 f0 = *(const uint4*)ap_;
      uint4 f1 = *(const uint4*)(ap_ + 4);
      uint4 hi4, lo4;
      hi4.x = rne_hi2(f0.x, f0.y); lo4.x = rne_lo2(f0.x, f0.y);
      hi4.y = rne_hi2(f0.z, f0.w); lo4.y = rne_lo2(f0.z, f0.w);
      hi4.z = rne_hi2(f1.x, f1.y); lo4.z = rne_lo2(f1.x, f1.y);
      hi4.w = rne_hi2(f1.z, f1.w); lo4.w = rne_lo2(f1.z, f1.w);
      *(uint4*)(&At[0][r * 40 + c8]) = hi4;
      *(uint4*)(&At[1][r * 40 + c8]) = lo4;
      *(uint4*)(&Bt[0][r * 40 + c8]) =
          *(const uint4*)(&Bhi[(size_t)(col0 + r) * K + k0 + c8]);
      *(uint4*)(&Bt[1][r * 40 + c8]) =
          *(const uint4*)(&Blo[(size_t)(col0 + r) * K + k0 + c8]);
    }
    __syncthreads();
    short8 ah[4], al[4], bh[4], bl[4];
    const int koff = quad * 8;
#pragma unroll
    for (int i = 0; i < 4; ++i) {
      ah[i] = *(const short8*)(&At[0][(wm + i * 16 + l15) * 40 + koff]);
      al[i] = *(const short8*)(&At[1][(wm + i * 16 + l15) * 40 + koff]);
      bh[i] = *(const short8*)(&Bt[0][(wn + i * 16 + l15) * 40 + koff]);
      bl[i] = *(const short8*)(&Bt[1][(wn + i * 16 + l15) * 40 + koff]);
    }
#pragma unroll
    for (int i = 0; i < 4; ++i)
#pragma unroll
      for (int j = 0; j < 4; ++j) {
        acc[i][j] = __builtin_amdgcn_mfma_f32_16x16x32_bf16(ah[i], bh[j], acc[i][j], 0, 0, 0);
        acc[i][j] = __builtin_amdgcn_mfma_f32_16x16x32_bf16(ah[i], bl[j], acc[i][j], 0, 0, 0);
        acc[i][j] = __builtin_amdgcn_mfma_f32_16x16x32_bf16(al[i], bh[j], acc[i][j], 0, 0, 0);
      }
    __syncthreads();
  }
#pragma unroll
  for (int j = 0; j < 4; ++j) {
    const int col = col0 + wn + j * 16 + l15;
    const float bv = bias ? bias[col] : 0.f;
#pragma unroll
    for (int i = 0; i < 4; ++i) {
#pragma unroll
      for (int r = 0; r < 4; ++r) {
        int row = row0 + wm + i * 16 + quad * 4 + r;
        C[(size_t)row * N + col] = acc[i][j][r] + bv;
      }
    }
  }
}

// ---------------------------------------------------------------- MFMA GEMM, spike-A 2-term
__global__ __launch_bounds__(256) void k_gemm_spike2(
    const float* __restrict__ A, const ushort_t* __restrict__ Bhi,
    const ushort_t* __restrict__ Blo, const float* __restrict__ bias,
    float* __restrict__ C, int M, int N, int K) {
  __shared__ ushort_t At[128 * 72];
  __shared__ ushort_t Bt[2][128 * 72];
  const int tid = threadIdx.x;
  const int row0 = blockIdx.x * 128, col0 = blockIdx.y * 128;
  const int w = tid >> 6, lane = tid & 63;
  const int wm = (w >> 1) * 64, wn = (w & 1) * 64;
  const int l15 = lane & 15, quad = lane >> 4;
  float4v acc[4][4];
#pragma unroll
  for (int i = 0; i < 4; ++i)
#pragma unroll
    for (int j = 0; j < 4; ++j) acc[i][j] = (float4v){0.f, 0.f, 0.f, 0.f};

  for (int k0 = 0; k0 < K; k0 += 64) {
#pragma unroll
    for (int it = 0; it < 4; ++it) {
      int idx = it * 256 + tid;          // 0..1023
      int r = idx >> 3;                  // row 0..127
      int c8 = (idx & 7) << 3;           // k-offset 0..56 step 8
      uint4 pa = *(const uint4*)(&A[(size_t)(row0 + r) * K + k0 + c8]);
      uint4 pb = *(const uint4*)(&A[(size_t)(row0 + r) * K + k0 + c8 + 4]);
      uint4 st;
      st.x = (pa.x >> 16) | (pa.y & 0xFFFF0000u);
      st.y = (pa.z >> 16) | (pa.w & 0xFFFF0000u);
      st.z = (pb.x >> 16) | (pb.y & 0xFFFF0000u);
      st.w = (pb.z >> 16) | (pb.w & 0xFFFF0000u);
      *(uint4*)(&At[r * 72 + c8]) = st;
      *(uint4*)(&Bt[0][r * 72 + c8]) =
          *(const uint4*)(&Bhi[(size_t)(col0 + r) * K + k0 + c8]);
      *(uint4*)(&Bt[1][r * 72 + c8]) =
          *(const uint4*)(&Blo[(size_t)(col0 + r) * K + k0 + c8]);
    }
    __syncthreads();
#pragma unroll
    for (int ks = 0; ks < 2; ++ks) {
      short8 a[4], bh[4], bl[4];
      const int koff = ks * 32 + quad * 8;
#pragma unroll
      for (int i = 0; i < 4; ++i) {
        a[i] = *(const short8*)(&At[(wm + i * 16 + l15) * 72 + koff]);
        bh[i] = *(const short8*)(&Bt[0][(wn + i * 16 + l15) * 72 + koff]);
        bl[i] = *(const short8*)(&Bt[1][(wn + i * 16 + l15) * 72 + koff]);
      }
#pragma unroll
      for (int i = 0; i < 4; ++i)
#pragma unroll
        for (int j = 0; j < 4; ++j) {
          acc[i][j] = __builtin_amdgcn_mfma_f32_16x16x32_bf16(a[i], bh[j], acc[i][j], 0, 0, 0);
          acc[i][j] = __builtin_amdgcn_mfma_f32_16x16x32_bf16(a[i], bl[j], acc[i][j], 0, 0, 0);
        }
    }
    __syncthreads();
  }
#pragma unroll
  for (int j = 0; j < 4; ++j) {
    const int col = col0 + wn + j * 16 + l15;
    const float bv = bias ? bias[col] : 0.f;
#pragma unroll
    for (int i = 0; i < 4; ++i) {
#pragma unroll
      for (int r = 0; r < 4; ++r) {
        int row = row0 + wm + i * 16 + quad * 4 + r;
        C[(size_t)row * N + col] = acc[i][j][r] + bv;
      }
    }
  }
}

// ---------------------------------------------------------------- LIF scan #1
__global__ __launch_bounds__(256) void k_lif1(float* __restrict__ p) {
  const int id = blockIdx.x * 256 + threadIdx.x;  // 0..32767
  const size_t base = (size_t)(id >> 9) * (T_STEPS * HID) + (id & 511);
  float mem = 0.f;
  for (int t0 = 0; t0 < T_STEPS; t0 += 8) {
    float v[8];
#pragma unroll
    for (int j = 0; j < 8; ++j) v[j] = p[base + (size_t)(t0 + j) * HID];
#pragma unroll
    for (int j = 0; j < 8; ++j) {
      float nm = BETA * mem + v[j];
      float sp = nm > THR ? 1.0f : 0.0f;
      p[base + (size_t)(t0 + j) * HID] = sp;
      mem = nm - sp;
    }
  }
}

// ---------------------------------------------------------------- recurrent scan (R11)
// R10 structure + drain-free barrier + depth-2 pipelined poll.
__global__ __launch_bounds__(512) void k_recurrent_cp(
    const float* __restrict__ W, const float* __restrict__ b_hh,
    float* __restrict__ rp, float* __restrict__ P) {
  const int tid = threadIdx.x;
  const int grp = blockIdx.x & 31;  // stride-32 members: same XCD under %8 RR
  const int j   = blockIdx.x >> 5;  // output-column block 0..7
  const int w   = tid >> 6;         // wave 0..7
  const int l   = tid & 63;
  const int q   = l >> 3;           // row-in-group 0..7
  const int c   = l & 7;            // k-chunk of this lane
  const int row = (w << 3) + q;     // 0..63 output row within block
  const int g0  = j << 6;

  __shared__ float memLDS[2][2][8 * 72];  // [parity][ob][chunk*72 + k]

  for (int i = tid; i < 2 * 2 * 8 * 72; i += 512) ((float*)memLDS)[i] = 0.f;

  float Wreg[64];
  {
    const float* wrow = W + (size_t)(g0 + row) * HID + (c << 6);
#pragma unroll
    for (int k4 = 0; k4 < 16; ++k4) {
      float4 w4 = *(const float4*)(wrow + 4 * k4);
      Wreg[4 * k4 + 0] = w4.x; Wreg[4 * k4 + 1] = w4.y;
      Wreg[4 * k4 + 2] = w4.z; Wreg[4 * k4 + 3] = w4.w;
    }
  }

  const bool lif = (c == 0);
  const int og = g0 + row;
  const size_t rp_b0 = (size_t)(grp * 2 + 0) * (T_STEPS * HID) + og;
  const size_t rp_b1 = (size_t)(grp * 2 + 1) * (T_STEPS * HID) + og;
  const float bhh_v = lif ? b_hh[og] : 0.f;
  float mem0 = 0.f, mem1 = 0.f;     // membrane registers (valid on lif lanes)

  const int rg = (tid < g0) ? tid : tid + 64;        // remote row (tid<448)
  const int raddr = (rg >> 6) * 72 + (rg & 63);

  u64_t* Pq = (u64_t*)P;

  __syncthreads();  // init barrier (one-time; full drain fine)

  for (int t = 0; t < T_STEPS; ++t) {
    const int par = t & 1;
    float ip0 = 0.f, ip1 = 0.f;
    if (lif) {
      ip0 = rp[rp_b0 + (size_t)t * HID];
      ip1 = rp[rp_b1 + (size_t)t * HID];
    }
    if (t > 0 && tid < 448) {
      const u64_t* ap = Pq + ((size_t)(t - 1) * 32 + grp) * 512 + rg;
      // depth-2 pipelined poll: check waits on a load issued one iteration
      // earlier; all loads compiler-managed (no asm on the data path).
      u64_t cur = __hip_atomic_load(ap, __ATOMIC_RELAXED, __HIP_MEMORY_SCOPE_AGENT);
      u64_t nx1 = __hip_atomic_load(ap, __ATOMIC_RELAXED, __HIP_MEMORY_SCOPE_AGENT);
      int tries = 0;
      while (((uint32_t)cur == SENT) || ((uint32_t)(cur >> 32) == SENT)) {
        cur = nx1;
        nx1 = __hip_atomic_load(ap, __ATOMIC_RELAXED, __HIP_MEMORY_SCOPE_AGENT);
        if (++tries > 24) __builtin_amdgcn_s_sleep(1);
      }
      memLDS[par][0][raddr] = __uint_as_float((uint32_t)cur);
      memLDS[par][1][raddr] = __uint_as_float((uint32_t)(cur >> 32));
    }
    // barrier WITHOUT vmcnt drain: cross-lane data is LDS-only (lgkmcnt);
    // the P store flies to the LLC while we proceed (no write-ack wait).
    asm volatile("s_waitcnt lgkmcnt(0)\n\ts_barrier" ::: "memory");

    float p0a = 0.f, p0b = 0.f, p1a = 0.f, p1b = 0.f;
    {
      const float4* m0 = (const float4*)&memLDS[par][0][c * 72];
      const float4* m1 = (const float4*)&memLDS[par][1][c * 72];
#pragma unroll
      for (int k4 = 0; k4 < 16; ++k4) {
        float4 a = m0[k4];
        float4 b = m1[k4];
        p0a = fmaf(Wreg[4 * k4 + 0], a.x, p0a);
        p0b = fmaf(Wreg[4 * k4 + 1], a.y, p0b);
        p0a = fmaf(Wreg[4 * k4 + 2], a.z, p0a);
        p0b = fmaf(Wreg[4 * k4 + 3], a.w, p0b);
        p1a = fmaf(Wreg[4 * k4 + 0], b.x, p1a);
        p1b = fmaf(Wreg[4 * k4 + 1], b.y, p1b);
        p1a = fmaf(Wreg[4 * k4 + 2], b.z, p1a);
        p1b = fmaf(Wreg[4 * k4 + 3], b.w, p1b);
      }
    }
    const int i0 = __float_as_int(p0a + p0b);
    const int i1 = __float_as_int(p1a + p1b);
    // serial ascending-chunk reduce across lanes (l&56)+ss  (== old scratch)
    float s0 = 0.f, s1 = 0.f;
#define RED(ss)                                                                 \
    s0 += __int_as_float(__builtin_amdgcn_ds_swizzle(i0, ((ss) << 5) | 0x18)); \
    s1 += __int_as_float(__builtin_amdgcn_ds_swizzle(i1, ((ss) << 5) | 0x18));
    RED(0) RED(1) RED(2) RED(3) RED(4) RED(5) RED(6) RED(7)
#undef RED

    if (lif) {
      const int npar = par ^ 1;
      const float nm0 = BETA * mem0 + ip0 + s0 + bhh_v;
      const float sp0 = nm0 > THR ? 1.0f : 0.0f;
      mem0 = nm0 - sp0;
      const float nm1 = BETA * mem1 + ip1 + s1 + bhh_v;
      const float sp1 = nm1 > THR ? 1.0f : 0.0f;
      mem1 = nm1 - sp1;
      const u64_t pk =
          ((u64_t)__float_as_uint(mem1) << 32) | (u64_t)__float_as_uint(mem0);
      __hip_atomic_store(Pq + ((size_t)t * 32 + grp) * 512 + og, pk,
                         __ATOMIC_RELAXED, __HIP_MEMORY_SCOPE_AGENT);
      rp[rp_b0 + (size_t)t * HID] = sp0;
      rp[rp_b1 + (size_t)t * HID] = sp1;
      memLDS[npar][0][j * 72 + row] = mem0;
      memLDS[npar][1][j * 72 + row] = mem1;
    }
  }
  // ensure all P/rp stores are globally visible before completion signal
  asm volatile("s_waitcnt vmcnt(0)" ::: "memory");
}

// ---------------------------------------------------------------- attend + threshold
__global__ __launch_bounds__(256) void k_attend(
    const float* __restrict__ op, const float* __restrict__ attn,
    const float* __restrict__ b_out, float* __restrict__ out) {
  const int b = blockIdx.x;
  const int o = threadIdx.x;
  float s = b_out[o];
  const float* opb = op + (size_t)b * T_STEPS * OUT_DIM + o;
  for (int t0 = 0; t0 < T_STEPS; t0 += 8) {
    float av[8], pv[8];
#pragma unroll
    for (int j = 0; j < 8; ++j) {
      av[j] = attn[(size_t)(t0 + j) * OUT_DIM + o];
      pv[j] = opb[(size_t)(t0 + j) * OUT_DIM];
    }
#pragma unroll
    for (int j = 0; j < 8; ++j) s = fmaf(av[j], pv[j], s);
  }
  out[b * OUT_DIM + o] = s > THR ? 1.0f : 0.0f;
}

// ---------------------------------------------------------------- launch
extern "C" void kernel_launch(void* const* d_in, const int* in_sizes, int n_in,
                              void* d_out, int out_size, void* d_ws, size_t ws_size,
                              hipStream_t stream) {
  (void)in_sizes; (void)n_in; (void)out_size; (void)ws_size;
  const float* x     = (const float*)d_in[0];
  const float* W_in  = (const float*)d_in[1];
  const float* b_in  = (const float*)d_in[2];
  const float* W_ih  = (const float*)d_in[3];
  const float* b_ih  = (const float*)d_in[4];
  const float* W_hh  = (const float*)d_in[5];
  const float* b_hh  = (const float*)d_in[6];
  const float* W_out = (const float*)d_in[7];
  const float* b_out = (const float*)d_in[8];
  const float* TA    = (const float*)d_in[9];

  float* ws = (float*)d_ws;
  float* proj  = ws;                           // 16.78M floats: GEMM1 out / P / out_proj
  float* rproj = proj + (size_t)32768 * 512;   // 16.78M floats: GEMM2 out
  float* attn  = rproj + (size_t)32768 * 512;  // 131072 floats
  ushort_t* wih_hi = (ushort_t*)(attn + 512 * 256);
  ushort_t* wih_lo = wih_hi + 512 * 512;
  ushort_t* win_hi = wih_lo + 512 * 512;
  ushort_t* win_lo = win_hi + 512 * 256;
  ushort_t* wout_hi = win_lo + 512 * 256;
  ushort_t* wout_lo = wout_hi + 256 * 512;
  float* P = proj;            // exchange slots [t][grp][row] qword pairs
  float* out_proj = proj;     // (b*T, O) fp32, written after recurrent

  k_softmax_t<<<8, 256, 0, stream>>>(TA, attn);
  k_split3w<<<512, 256, 0, stream>>>(W_in, win_hi, win_lo,
                                     W_ih, wih_hi, wih_lo,
                                     W_out, wout_hi, wout_lo);

  // GEMM1: proj = x @ W_in^T + b_in   (M=32768, N=512, K=256), x split fused
  k_gemm_fsplit3<<<dim3(256, 4), 256, 0, stream>>>(
      x, win_hi, win_lo, b_in, proj, 32768, 512, 256);
  k_lif1<<<128, 256, 0, stream>>>(proj);
  // GEMM2: rproj = spikes @ W_ih^T + b_ih   (M=32768, N=512, K=512)
  k_gemm_spike2<<<dim3(256, 4), 256, 0, stream>>>(
      proj, wih_hi, wih_lo, b_ih, rproj, 32768, 512, 512);
  k_fill_nan<<<256, 256, 0, stream>>>((uint32_t*)P);  // proj dead after GEMM2
  k_recurrent_cp<<<256, 512, 0, stream>>>(W_hh, b_hh, rproj, P);
  // GEMM3: out_proj = tspikes @ W_out^T   (M=32768, N=256, K=512, no bias)
  k_gemm_spike2<<<dim3(256, 2), 256, 0, stream>>>(
      rproj, wout_hi, wout_lo, nullptr, out_proj, 32768, 256, 512);
  k_attend<<<64, 256, 0, stream>>>(out_proj, attn, b_out, (float*)d_out);
}

// Round 8
// 1025.554 us; speedup vs baseline: 1.3280x; 1.3280x over previous
//
#include <hip/hip_runtime.h>
#include <hip/hip_bf16.h>
#include <cstdint>

// PhaseEncodingSNN: B=64, T=512, I=256, H=512, O=256.
// R12: scan reverted to R10-EXACT structure (proven 748us) with ONE change:
//  - 16B poll granule: 224 lanes poll dwordx4 (2 rows/lane) instead of 448
//    lanes x 8B. Halves LLC poll requests (R7/R11: poll traffic raises LLC
//    service latency). asm block contains load + s_waitcnt vmcnt(0) TOGETHER
//    -> no in-flight reg crosses C control flow (R9 lesson). sc1 = L1-bypass
//    (R6 lesson: anything weaker spins on stale L1).
//  - k_split3w merge kept from R11 (correctness-validated there; -2 launches).
// R11 post-mortem: depth-2 poll +60% traffic = regression; drain-free barrier
// gains nothing (vmcnt retires IN ORDER -> poll already waits the store).
// Everything else bitwise == R10 (qword exchange, full-drain __syncthreads,
// fused x-split GEMM1, fmaf order, swizzle reduce, LIF, store order).

#define T_STEPS 512
#define BATCH 64
#define HID 512
#define IN_DIM 256
#define OUT_DIM 256
#define BETA 0.9f
#define THR 1.0f
#define SENT 0x7FC00000u

typedef __attribute__((ext_vector_type(8))) short short8;
typedef __attribute__((ext_vector_type(4))) float float4v;
typedef __attribute__((ext_vector_type(4))) unsigned int uint32x4;
typedef unsigned short ushort_t;
typedef unsigned long long u64_t;

// ---------------------------------------------------------------- NaN fill
__global__ __launch_bounds__(256) void k_fill_nan(uint32_t* __restrict__ P) {
  const int idx = blockIdx.x * 256 + threadIdx.x;  // 65536 threads
  uint4 s = make_uint4(SENT, SENT, SENT, SENT);
  uint4* p4 = (uint4*)P;
  for (int i = idx; i < (32768 * 512) / 4; i += 65536) p4[i] = s;
}

// ---------------------------------------------------------------- fp32 -> hi/lo bf16 split
__device__ __forceinline__ void split1(float v, ushort_t* hi, ushort_t* lo) {
  uint32_t u = __float_as_uint(v);
  uint32_t rh = u + 0x7FFFu + ((u >> 16) & 1u);   // RNE to bf16
  ushort_t h = (ushort_t)(rh >> 16);
  float hf = __uint_as_float(((uint32_t)h) << 16);
  float l = v - hf;
  uint32_t ul = __float_as_uint(l);
  uint32_t rl = ul + 0x7FFFu + ((ul >> 16) & 1u);
  *hi = h;
  *lo = (ushort_t)(rl >> 16);
}

// merged weight splits: [0,131072) W_in, [131072,393216) W_ih,
// [393216,524288) W_out.
__global__ __launch_bounds__(256) void k_split3w(
    const float* __restrict__ W_in, ushort_t* __restrict__ win_hi, ushort_t* __restrict__ win_lo,
    const float* __restrict__ W_ih, ushort_t* __restrict__ wih_hi, ushort_t* __restrict__ wih_lo,
    const float* __restrict__ W_out, ushort_t* __restrict__ wout_hi, ushort_t* __restrict__ wout_lo) {
  int i = blockIdx.x * 256 + threadIdx.x;
  for (; i < 524288; i += 131072) {
    const float* src; ushort_t* hi; ushort_t* lo; int off;
    if (i < 131072)      { src = W_in;  hi = win_hi;  lo = win_lo;  off = i; }
    else if (i < 393216) { src = W_ih;  hi = wih_hi;  lo = wih_lo;  off = i - 131072; }
    else                 { src = W_out; hi = wout_hi; lo = wout_lo; off = i - 393216; }
    split1(src[off], hi + off, lo + off);
  }
}

// split helpers (bitwise-identical math), 2 elems -> packed u32
__device__ __forceinline__ uint32_t rne_hi2(uint32_t ua, uint32_t ub) {
  uint32_t ra = ua + 0x7FFFu + ((ua >> 16) & 1u);
  uint32_t rb = ub + 0x7FFFu + ((ub >> 16) & 1u);
  return (ra >> 16) | (rb & 0xFFFF0000u);
}
__device__ __forceinline__ uint32_t rne_lo2(uint32_t ua, uint32_t ub) {
  uint32_t ra = ua + 0x7FFFu + ((ua >> 16) & 1u);
  uint32_t rb = ub + 0x7FFFu + ((ub >> 16) & 1u);
  float la = __uint_as_float(ua) - __uint_as_float(ra & 0xFFFF0000u);
  float lb = __uint_as_float(ub) - __uint_as_float(rb & 0xFFFF0000u);
  uint32_t ula = __float_as_uint(la), ulb = __float_as_uint(lb);
  uint32_t rla = ula + 0x7FFFu + ((ula >> 16) & 1u);
  uint32_t rlb = ulb + 0x7FFFu + ((ulb >> 16) & 1u);
  return (rla >> 16) | (rlb & 0xFFFF0000u);
}

// ---------------------------------------------------------------- softmax over t
__global__ __launch_bounds__(256) void k_softmax_t(
    const float* __restrict__ TA, float* __restrict__ attn) {
  __shared__ float redm[8][32];
  __shared__ float reds[8][32];
  const int ol = threadIdx.x & 31;
  const int tg = threadIdx.x >> 5;
  const int o = blockIdx.x * 32 + ol;
  float mx = -1e30f;
  for (int i = 0; i < 64; ++i) {
    float v = TA[(size_t)(tg * 64 + i) * OUT_DIM + o];
    mx = fmaxf(mx, v);
  }
  redm[tg][ol] = mx;
  __syncthreads();
  float m = redm[0][ol];
#pragma unroll
  for (int j = 1; j < 8; ++j) m = fmaxf(m, redm[j][ol]);
  float s = 0.f;
  for (int i = 0; i < 64; ++i) {
    float v = TA[(size_t)(tg * 64 + i) * OUT_DIM + o];
    s += __expf(v - m);
  }
  reds[tg][ol] = s;
  __syncthreads();
  float tot = 0.f;
#pragma unroll
  for (int j = 0; j < 8; ++j) tot += reds[j][ol];
  const float inv = 1.0f / tot;
  for (int i = 0; i < 64; ++i) {
    int t = tg * 64 + i;
    float v = TA[(size_t)t * OUT_DIM + o];
    attn[(size_t)t * OUT_DIM + o] = __expf(v - m) * inv;
  }
}

// ---------------------------------------------------------------- MFMA GEMM, fused-split A (x fp32), 3-term
__global__ __launch_bounds__(256) void k_gemm_fsplit3(
    const float* __restrict__ A, const ushort_t* __restrict__ Bhi,
    const ushort_t* __restrict__ Blo, const float* __restrict__ bias,
    float* __restrict__ C, int M, int N, int K) {
  __shared__ ushort_t At[2][128 * 40];
  __shared__ ushort_t Bt[2][128 * 40];
  const int tid = threadIdx.x;
  const int row0 = blockIdx.x * 128, col0 = blockIdx.y * 128;
  const int w = tid >> 6, lane = tid & 63;
  const int wm = (w >> 1) * 64, wn = (w & 1) * 64;
  const int l15 = lane & 15, quad = lane >> 4;
  float4v acc[4][4];
#pragma unroll
  for (int i = 0; i < 4; ++i)
#pragma unroll
    for (int j = 0; j < 4; ++j) acc[i][j] = (float4v){0.f, 0.f, 0.f, 0.f};

  for (int k0 = 0; k0 < K; k0 += 32) {
#pragma unroll
    for (int it = 0; it < 2; ++it) {
      int idx = it * 256 + tid;          // 0..511
      int r = idx >> 2;                  // row 0..127
      int c8 = (idx & 3) << 3;           // k-offset {0,8,16,24}
      const float* ap_ = &A[(size_t)(row0 + r) * K + k0 + c8];
      uint4 f0 = *(const uint4*)ap_;
      uint4 f1 = *(const uint4*)(ap_ + 4);
      uint4 hi4, lo4;
      hi4.x = rne_hi2(f0.x, f0.y); lo4.x = rne_lo2(f0.x, f0.y);
      hi4.y = rne_hi2(f0.z, f0.w); lo4.y = rne_lo2(f0.z, f0.w);
      hi4.z = rne_hi2(f1.x, f1.y); lo4.z = rne_lo2(f1.x, f1.y);
      hi4.w = rne_hi2(f1.z, f1.w); lo4.w = rne_lo2(f1.z, f1.w);
      *(uint4*)(&At[0][r * 40 + c8]) = hi4;
      *(uint4*)(&At[1][r * 40 + c8]) = lo4;
      *(uint4*)(&Bt[0][r * 40 + c8]) =
          *(const uint4*)(&Bhi[(size_t)(col0 + r) * K + k0 + c8]);
      *(uint4*)(&Bt[1][r * 40 + c8]) =
          *(const uint4*)(&Blo[(size_t)(col0 + r) * K + k0 + c8]);
    }
    __syncthreads();
    short8 ah[4], al[4], bh[4], bl[4];
    const int koff = quad * 8;
#pragma unroll
    for (int i = 0; i < 4; ++i) {
      ah[i] = *(const short8*)(&At[0][(wm + i * 16 + l15) * 40 + koff]);
      al[i] = *(const short8*)(&At[1][(wm + i * 16 + l15) * 40 + koff]);
      bh[i] = *(const short8*)(&Bt[0][(wn + i * 16 + l15) * 40 + koff]);
      bl[i] = *(const short8*)(&Bt[1][(wn + i * 16 + l15) * 40 + koff]);
    }
#pragma unroll
    for (int i = 0; i < 4; ++i)
#pragma unroll
      for (int j = 0; j < 4; ++j) {
        acc[i][j] = __builtin_amdgcn_mfma_f32_16x16x32_bf16(ah[i], bh[j], acc[i][j], 0, 0, 0);
        acc[i][j] = __builtin_amdgcn_mfma_f32_16x16x32_bf16(ah[i], bl[j], acc[i][j], 0, 0, 0);
        acc[i][j] = __builtin_amdgcn_mfma_f32_16x16x32_bf16(al[i], bh[j], acc[i][j], 0, 0, 0);
      }
    __syncthreads();
  }
#pragma unroll
  for (int j = 0; j < 4; ++j) {
    const int col = col0 + wn + j * 16 + l15;
    const float bv = bias ? bias[col] : 0.f;
#pragma unroll
    for (int i = 0; i < 4; ++i) {
#pragma unroll
      for (int r = 0; r < 4; ++r) {
        int row = row0 + wm + i * 16 + quad * 4 + r;
        C[(size_t)row * N + col] = acc[i][j][r] + bv;
      }
    }
  }
}

// ---------------------------------------------------------------- MFMA GEMM, spike-A 2-term
__global__ __launch_bounds__(256) void k_gemm_spike2(
    const float* __restrict__ A, const ushort_t* __restrict__ Bhi,
    const ushort_t* __restrict__ Blo, const float* __restrict__ bias,
    float* __restrict__ C, int M, int N, int K) {
  __shared__ ushort_t At[128 * 72];
  __shared__ ushort_t Bt[2][128 * 72];
  const int tid = threadIdx.x;
  const int row0 = blockIdx.x * 128, col0 = blockIdx.y * 128;
  const int w = tid >> 6, lane = tid & 63;
  const int wm = (w >> 1) * 64, wn = (w & 1) * 64;
  const int l15 = lane & 15, quad = lane >> 4;
  float4v acc[4][4];
#pragma unroll
  for (int i = 0; i < 4; ++i)
#pragma unroll
    for (int j = 0; j < 4; ++j) acc[i][j] = (float4v){0.f, 0.f, 0.f, 0.f};

  for (int k0 = 0; k0 < K; k0 += 64) {
#pragma unroll
    for (int it = 0; it < 4; ++it) {
      int idx = it * 256 + tid;          // 0..1023
      int r = idx >> 3;                  // row 0..127
      int c8 = (idx & 7) << 3;           // k-offset 0..56 step 8
      uint4 pa = *(const uint4*)(&A[(size_t)(row0 + r) * K + k0 + c8]);
      uint4 pb = *(const uint4*)(&A[(size_t)(row0 + r) * K + k0 + c8 + 4]);
      uint4 st;
      st.x = (pa.x >> 16) | (pa.y & 0xFFFF0000u);
      st.y = (pa.z >> 16) | (pa.w & 0xFFFF0000u);
      st.z = (pb.x >> 16) | (pb.y & 0xFFFF0000u);
      st.w = (pb.z >> 16) | (pb.w & 0xFFFF0000u);
      *(uint4*)(&At[r * 72 + c8]) = st;
      *(uint4*)(&Bt[0][r * 72 + c8]) =
          *(const uint4*)(&Bhi[(size_t)(col0 + r) * K + k0 + c8]);
      *(uint4*)(&Bt[1][r * 72 + c8]) =
          *(const uint4*)(&Blo[(size_t)(col0 + r) * K + k0 + c8]);
    }
    __syncthreads();
#pragma unroll
    for (int ks = 0; ks < 2; ++ks) {
      short8 a[4], bh[4], bl[4];
      const int koff = ks * 32 + quad * 8;
#pragma unroll
      for (int i = 0; i < 4; ++i) {
        a[i] = *(const short8*)(&At[(wm + i * 16 + l15) * 72 + koff]);
        bh[i] = *(const short8*)(&Bt[0][(wn + i * 16 + l15) * 72 + koff]);
        bl[i] = *(const short8*)(&Bt[1][(wn + i * 16 + l15) * 72 + koff]);
      }
#pragma unroll
      for (int i = 0; i < 4; ++i)
#pragma unroll
        for (int j = 0; j < 4; ++j) {
          acc[i][j] = __builtin_amdgcn_mfma_f32_16x16x32_bf16(a[i], bh[j], acc[i][j], 0, 0, 0);
          acc[i][j] = __builtin_amdgcn_mfma_f32_16x16x32_bf16(a[i], bl[j], acc[i][j], 0, 0, 0);
        }
    }
    __syncthreads();
  }
#pragma unroll
  for (int j = 0; j < 4; ++j) {
    const int col = col0 + wn + j * 16 + l15;
    const float bv = bias ? bias[col] : 0.f;
#pragma unroll
    for (int i = 0; i < 4; ++i) {
#pragma unroll
      for (int r = 0; r < 4; ++r) {
        int row = row0 + wm + i * 16 + quad * 4 + r;
        C[(size_t)row * N + col] = acc[i][j][r] + bv;
      }
    }
  }
}

// ---------------------------------------------------------------- LIF scan #1
__global__ __launch_bounds__(256) void k_lif1(float* __restrict__ p) {
  const int id = blockIdx.x * 256 + threadIdx.x;  // 0..32767
  const size_t base = (size_t)(id >> 9) * (T_STEPS * HID) + (id & 511);
  float mem = 0.f;
  for (int t0 = 0; t0 < T_STEPS; t0 += 8) {
    float v[8];
#pragma unroll
    for (int j = 0; j < 8; ++j) v[j] = p[base + (size_t)(t0 + j) * HID];
#pragma unroll
    for (int j = 0; j < 8; ++j) {
      float nm = BETA * mem + v[j];
      float sp = nm > THR ? 1.0f : 0.0f;
      p[base + (size_t)(t0 + j) * HID] = sp;
      mem = nm - sp;
    }
  }
}

// ---------------------------------------------------------------- recurrent scan (R12)
// R10-exact structure; poll granule widened to 16B (2 rows per polling lane,
// 224 lanes). asm block = load + s_waitcnt together (no in-flight escape).
__global__ __launch_bounds__(512) void k_recurrent_cp(
    const float* __restrict__ W, const float* __restrict__ b_hh,
    float* __restrict__ rp, float* __restrict__ P) {
  const int tid = threadIdx.x;
  const int grp = blockIdx.x & 31;  // stride-32 members: same XCD under %8 RR
  const int j   = blockIdx.x >> 5;  // output-column block 0..7
  const int w   = tid >> 6;         // wave 0..7
  const int l   = tid & 63;
  const int q   = l >> 3;           // row-in-group 0..7
  const int c   = l & 7;            // k-chunk of this lane
  const int row = (w << 3) + q;     // 0..63 output row within block
  const int g0  = j << 6;

  __shared__ float memLDS[2][2][8 * 72];  // [parity][ob][chunk*72 + k]

  for (int i = tid; i < 2 * 2 * 8 * 72; i += 512) ((float*)memLDS)[i] = 0.f;

  float Wreg[64];
  {
    const float* wrow = W + (size_t)(g0 + row) * HID + (c << 6);
#pragma unroll
    for (int k4 = 0; k4 < 16; ++k4) {
      float4 w4 = *(const float4*)(wrow + 4 * k4);
      Wreg[4 * k4 + 0] = w4.x; Wreg[4 * k4 + 1] = w4.y;
      Wreg[4 * k4 + 2] = w4.z; Wreg[4 * k4 + 3] = w4.w;
    }
  }

  const bool lif = (c == 0);
  const int og = g0 + row;
  const size_t rp_b0 = (size_t)(grp * 2 + 0) * (T_STEPS * HID) + og;
  const size_t rp_b1 = (size_t)(grp * 2 + 1) * (T_STEPS * HID) + og;
  const float bhh_v = lif ? b_hh[og] : 0.f;
  float mem0 = 0.f, mem1 = 0.f;     // membrane registers (valid on lif lanes)

  // 16B poll mapping: 224 lanes handle the 224 remote row-PAIRS (own 32
  // pairs [g0/2, g0/2+32) skipped; pairs never straddle the own window).
  const int pidx = (tid < (g0 >> 1)) ? tid : tid + 32;   // used when tid<224
  const int r0 = pidx << 1;
  const int ra = ((r0 >> 6) * 72) + (r0 & 63);

  u64_t* Pq = (u64_t*)P;

  __syncthreads();

  for (int t = 0; t < T_STEPS; ++t) {
    const int par = t & 1;
    float ip0 = 0.f, ip1 = 0.f;
    if (lif) {
      ip0 = rp[rp_b0 + (size_t)t * HID];
      ip1 = rp[rp_b1 + (size_t)t * HID];
    }
    if (t > 0 && tid < 224) {
      const uint32x4* ap =
          (const uint32x4*)(Pq + ((size_t)(t - 1) * 32 + grp) * 512) + pidx;
      uint32x4 u;
      int tries = 0;
      for (;;) {
        // load + wait in ONE asm block: result fully materialized at exit,
        // no in-flight register crosses C control flow (R9 lesson).
        asm volatile("global_load_dwordx4 %0, %1, off sc1\n\t"
                     "s_waitcnt vmcnt(0)"
                     : "=v"(u) : "v"(ap) : "memory");
        if (u.x != SENT && u.y != SENT && u.z != SENT && u.w != SENT) break;
        if (++tries > 24) __builtin_amdgcn_s_sleep(1);
      }
      memLDS[par][0][ra]     = __uint_as_float(u.x);
      memLDS[par][1][ra]     = __uint_as_float(u.y);
      memLDS[par][0][ra + 1] = __uint_as_float(u.z);
      memLDS[par][1][ra + 1] = __uint_as_float(u.w);
    }
    __syncthreads();

    float p0a = 0.f, p0b = 0.f, p1a = 0.f, p1b = 0.f;
    {
      const float4* m0 = (const float4*)&memLDS[par][0][c * 72];
      const float4* m1 = (const float4*)&memLDS[par][1][c * 72];
#pragma unroll
      for (int k4 = 0; k4 < 16; ++k4) {
        float4 a = m0[k4];
        float4 b = m1[k4];
        p0a = fmaf(Wreg[4 * k4 + 0], a.x, p0a);
        p0b = fmaf(Wreg[4 * k4 + 1], a.y, p0b);
        p0a = fmaf(Wreg[4 * k4 + 2], a.z, p0a);
        p0b = fmaf(Wreg[4 * k4 + 3], a.w, p0b);
        p1a = fmaf(Wreg[4 * k4 + 0], b.x, p1a);
        p1b = fmaf(Wreg[4 * k4 + 1], b.y, p1b);
        p1a = fmaf(Wreg[4 * k4 + 2], b.z, p1a);
        p1b = fmaf(Wreg[4 * k4 + 3], b.w, p1b);
      }
    }
    const int i0 = __float_as_int(p0a + p0b);
    const int i1 = __float_as_int(p1a + p1b);
    // serial ascending-chunk reduce across lanes (l&56)+ss  (== old scratch)
    float s0 = 0.f, s1 = 0.f;
#define RED(ss)                                                                 \
    s0 += __int_as_float(__builtin_amdgcn_ds_swizzle(i0, ((ss) << 5) | 0x18)); \
    s1 += __int_as_float(__builtin_amdgcn_ds_swizzle(i1, ((ss) << 5) | 0x18));
    RED(0) RED(1) RED(2) RED(3) RED(4) RED(5) RED(6) RED(7)
#undef RED

    if (lif) {
      const int npar = par ^ 1;
      const float nm0 = BETA * mem0 + ip0 + s0 + bhh_v;
      const float sp0 = nm0 > THR ? 1.0f : 0.0f;
      mem0 = nm0 - sp0;
      const float nm1 = BETA * mem1 + ip1 + s1 + bhh_v;
      const float sp1 = nm1 > THR ? 1.0f : 0.0f;
      mem1 = nm1 - sp1;
      const u64_t pk =
          ((u64_t)__float_as_uint(mem1) << 32) | (u64_t)__float_as_uint(mem0);
      __hip_atomic_store(Pq + ((size_t)t * 32 + grp) * 512 + og, pk,
                         __ATOMIC_RELAXED, __HIP_MEMORY_SCOPE_AGENT);
      rp[rp_b0 + (size_t)t * HID] = sp0;
      rp[rp_b1 + (size_t)t * HID] = sp1;
      memLDS[npar][0][j * 72 + row] = mem0;
      memLDS[npar][1][j * 72 + row] = mem1;
    }
  }
}

// ---------------------------------------------------------------- attend + threshold
__global__ __launch_bounds__(256) void k_attend(
    const float* __restrict__ op, const float* __restrict__ attn,
    const float* __restrict__ b_out, float* __restrict__ out) {
  const int b = blockIdx.x;
  const int o = threadIdx.x;
  float s = b_out[o];
  const float* opb = op + (size_t)b * T_STEPS * OUT_DIM + o;
  for (int t0 = 0; t0 < T_STEPS; t0 += 8) {
    float av[8], pv[8];
#pragma unroll
    for (int j = 0; j < 8; ++j) {
      av[j] = attn[(size_t)(t0 + j) * OUT_DIM + o];
      pv[j] = opb[(size_t)(t0 + j) * OUT_DIM];
    }
#pragma unroll
    for (int j = 0; j < 8; ++j) s = fmaf(av[j], pv[j], s);
  }
  out[b * OUT_DIM + o] = s > THR ? 1.0f : 0.0f;
}

// ---------------------------------------------------------------- launch
extern "C" void kernel_launch(void* const* d_in, const int* in_sizes, int n_in,
                              void* d_out, int out_size, void* d_ws, size_t ws_size,
                              hipStream_t stream) {
  (void)in_sizes; (void)n_in; (void)out_size; (void)ws_size;
  const float* x     = (const float*)d_in[0];
  const float* W_in  = (const float*)d_in[1];
  const float* b_in  = (const float*)d_in[2];
  const float* W_ih  = (const float*)d_in[3];
  const float* b_ih  = (const float*)d_in[4];
  const float* W_hh  = (const float*)d_in[5];
  const float* b_hh  = (const float*)d_in[6];
  const float* W_out = (const float*)d_in[7];
  const float* b_out = (const float*)d_in[8];
  const float* TA    = (const float*)d_in[9];

  float* ws = (float*)d_ws;
  float* proj  = ws;                           // 16.78M floats: GEMM1 out / P / out_proj
  float* rproj = proj + (size_t)32768 * 512;   // 16.78M floats: GEMM2 out
  float* attn  = rproj + (size_t)32768 * 512;  // 131072 floats
  ushort_t* wih_hi = (ushort_t*)(attn + 512 * 256);
  ushort_t* wih_lo = wih_hi + 512 * 512;
  ushort_t* win_hi = wih_lo + 512 * 512;
  ushort_t* win_lo = win_hi + 512 * 256;
  ushort_t* wout_hi = win_lo + 512 * 256;
  ushort_t* wout_lo = wout_hi + 256 * 512;
  float* P = proj;            // exchange slots [t][grp][row] qword pairs
  float* out_proj = proj;     // (b*T, O) fp32, written after recurrent

  k_softmax_t<<<8, 256, 0, stream>>>(TA, attn);
  k_split3w<<<512, 256, 0, stream>>>(W_in, win_hi, win_lo,
                                     W_ih, wih_hi, wih_lo,
                                     W_out, wout_hi, wout_lo);

  // GEMM1: proj = x @ W_in^T + b_in   (M=32768, N=512, K=256), x split fused
  k_gemm_fsplit3<<<dim3(256, 4), 256, 0, stream>>>(
      x, win_hi, win_lo, b_in, proj, 32768, 512, 256);
  k_lif1<<<128, 256, 0, stream>>>(proj);
  // GEMM2: rproj = spikes @ W_ih^T + b_ih   (M=32768, N=512, K=512)
  k_gemm_spike2<<<dim3(256, 4), 256, 0, stream>>>(
      proj, wih_hi, wih_lo, b_ih, rproj, 32768, 512, 512);
  k_fill_nan<<<256, 256, 0, stream>>>((uint32_t*)P);  // proj dead after GEMM2
  k_recurrent_cp<<<256, 512, 0, stream>>>(W_hh, b_hh, rproj, P);
  // GEMM3: out_proj = tspikes @ W_out^T   (M=32768, N=256, K=512, no bias)
  k_gemm_spike2<<<dim3(256, 2), 256, 0, stream>>>(
      rproj, wout_hi, wout_lo, nullptr, out_proj, 32768, 256, 512);
  k_attend<<<64, 256, 0, stream>>>(out_proj, attn, b_out, (float*)d_out);
}

// Round 9
// 981.030 us; speedup vs baseline: 1.3883x; 1.0454x over previous
//
#include <hip/hip_runtime.h>
#include <hip/hip_bf16.h>
#include <cstdint>

// PhaseEncodingSNN: B=64, T=512, I=256, H=512, O=256.
// R13: CONSOLIDATION. Scan reverted to R10-exact (proven 748us): 448-lane
// 8B compiler-managed agent-scope atomic polls, full-drain __syncthreads.
// Kept (validated in R11/R12): k_split3w merged weight splits, fused x-split
// GEMM1 (k_gemm_fsplit3).
// Closed case from R5-R12 experiments on the scan's ~2300cy LLC hop:
//  R6: sc0 loads don't bypass L1 (stale spin, 26x). R7: poll duplication
//  congests LLC (2x). R8: L2 fast-rail never validates (+overhead).
//  R9: in-flight asm loads crossing C control flow = UB (absmax fail).
//  R11: deeper poll = +traffic = regression; drain-free barrier = null
//  (vmcnt retires in-order; poll already serializes behind the store).
//  R12: wider poll = serialized rounds = regression.
// The scan is latency-bound (one LLC round-trip per serial step x 512);
// counters: VALUBusy ~38%, HBM ~3%, MfmaUtil 0, conflicts 0.

#define T_STEPS 512
#define BATCH 64
#define HID 512
#define IN_DIM 256
#define OUT_DIM 256
#define BETA 0.9f
#define THR 1.0f
#define SENT 0x7FC00000u

typedef __attribute__((ext_vector_type(8))) short short8;
typedef __attribute__((ext_vector_type(4))) float float4v;
typedef unsigned short ushort_t;
typedef unsigned long long u64_t;

// ---------------------------------------------------------------- NaN fill
__global__ __launch_bounds__(256) void k_fill_nan(uint32_t* __restrict__ P) {
  const int idx = blockIdx.x * 256 + threadIdx.x;  // 65536 threads
  uint4 s = make_uint4(SENT, SENT, SENT, SENT);
  uint4* p4 = (uint4*)P;
  for (int i = idx; i < (32768 * 512) / 4; i += 65536) p4[i] = s;
}

// ---------------------------------------------------------------- fp32 -> hi/lo bf16 split
__device__ __forceinline__ void split1(float v, ushort_t* hi, ushort_t* lo) {
  uint32_t u = __float_as_uint(v);
  uint32_t rh = u + 0x7FFFu + ((u >> 16) & 1u);   // RNE to bf16
  ushort_t h = (ushort_t)(rh >> 16);
  float hf = __uint_as_float(((uint32_t)h) << 16);
  float l = v - hf;
  uint32_t ul = __float_as_uint(l);
  uint32_t rl = ul + 0x7FFFu + ((ul >> 16) & 1u);
  *hi = h;
  *lo = (ushort_t)(rl >> 16);
}

// merged weight splits: [0,131072) W_in, [131072,393216) W_ih,
// [393216,524288) W_out.
__global__ __launch_bounds__(256) void k_split3w(
    const float* __restrict__ W_in, ushort_t* __restrict__ win_hi, ushort_t* __restrict__ win_lo,
    const float* __restrict__ W_ih, ushort_t* __restrict__ wih_hi, ushort_t* __restrict__ wih_lo,
    const float* __restrict__ W_out, ushort_t* __restrict__ wout_hi, ushort_t* __restrict__ wout_lo) {
  int i = blockIdx.x * 256 + threadIdx.x;
  for (; i < 524288; i += 131072) {
    const float* src; ushort_t* hi; ushort_t* lo; int off;
    if (i < 131072)      { src = W_in;  hi = win_hi;  lo = win_lo;  off = i; }
    else if (i < 393216) { src = W_ih;  hi = wih_hi;  lo = wih_lo;  off = i - 131072; }
    else                 { src = W_out; hi = wout_hi; lo = wout_lo; off = i - 393216; }
    split1(src[off], hi + off, lo + off);
  }
}

// split helpers (bitwise-identical math), 2 elems -> packed u32
__device__ __forceinline__ uint32_t rne_hi2(uint32_t ua, uint32_t ub) {
  uint32_t ra = ua + 0x7FFFu + ((ua >> 16) & 1u);
  uint32_t rb = ub + 0x7FFFu + ((ub >> 16) & 1u);
  return (ra >> 16) | (rb & 0xFFFF0000u);
}
__device__ __forceinline__ uint32_t rne_lo2(uint32_t ua, uint32_t ub) {
  uint32_t ra = ua + 0x7FFFu + ((ua >> 16) & 1u);
  uint32_t rb = ub + 0x7FFFu + ((ub >> 16) & 1u);
  float la = __uint_as_float(ua) - __uint_as_float(ra & 0xFFFF0000u);
  float lb = __uint_as_float(ub) - __uint_as_float(rb & 0xFFFF0000u);
  uint32_t ula = __float_as_uint(la), ulb = __float_as_uint(lb);
  uint32_t rla = ula + 0x7FFFu + ((ula >> 16) & 1u);
  uint32_t rlb = ulb + 0x7FFFu + ((ulb >> 16) & 1u);
  return (rla >> 16) | (rlb & 0xFFFF0000u);
}

// ---------------------------------------------------------------- softmax over t
__global__ __launch_bounds__(256) void k_softmax_t(
    const float* __restrict__ TA, float* __restrict__ attn) {
  __shared__ float redm[8][32];
  __shared__ float reds[8][32];
  const int ol = threadIdx.x & 31;
  const int tg = threadIdx.x >> 5;
  const int o = blockIdx.x * 32 + ol;
  float mx = -1e30f;
  for (int i = 0; i < 64; ++i) {
    float v = TA[(size_t)(tg * 64 + i) * OUT_DIM + o];
    mx = fmaxf(mx, v);
  }
  redm[tg][ol] = mx;
  __syncthreads();
  float m = redm[0][ol];
#pragma unroll
  for (int j = 1; j < 8; ++j) m = fmaxf(m, redm[j][ol]);
  float s = 0.f;
  for (int i = 0; i < 64; ++i) {
    float v = TA[(size_t)(tg * 64 + i) * OUT_DIM + o];
    s += __expf(v - m);
  }
  reds[tg][ol] = s;
  __syncthreads();
  float tot = 0.f;
#pragma unroll
  for (int j = 0; j < 8; ++j) tot += reds[j][ol];
  const float inv = 1.0f / tot;
  for (int i = 0; i < 64; ++i) {
    int t = tg * 64 + i;
    float v = TA[(size_t)t * OUT_DIM + o];
    attn[(size_t)t * OUT_DIM + o] = __expf(v - m) * inv;
  }
}

// ---------------------------------------------------------------- MFMA GEMM, fused-split A (x fp32), 3-term
__global__ __launch_bounds__(256) void k_gemm_fsplit3(
    const float* __restrict__ A, const ushort_t* __restrict__ Bhi,
    const ushort_t* __restrict__ Blo, const float* __restrict__ bias,
    float* __restrict__ C, int M, int N, int K) {
  __shared__ ushort_t At[2][128 * 40];
  __shared__ ushort_t Bt[2][128 * 40];
  const int tid = threadIdx.x;
  const int row0 = blockIdx.x * 128, col0 = blockIdx.y * 128;
  const int w = tid >> 6, lane = tid & 63;
  const int wm = (w >> 1) * 64, wn = (w & 1) * 64;
  const int l15 = lane & 15, quad = lane >> 4;
  float4v acc[4][4];
#pragma unroll
  for (int i = 0; i < 4; ++i)
#pragma unroll
    for (int j = 0; j < 4; ++j) acc[i][j] = (float4v){0.f, 0.f, 0.f, 0.f};

  for (int k0 = 0; k0 < K; k0 += 32) {
#pragma unroll
    for (int it = 0; it < 2; ++it) {
      int idx = it * 256 + tid;          // 0..511
      int r = idx >> 2;                  // row 0..127
      int c8 = (idx & 3) << 3;           // k-offset {0,8,16,24}
      const float* ap_ = &A[(size_t)(row0 + r) * K + k0 + c8];
      uint4 f0 = *(const uint4*)ap_;
      uint4 f1 = *(const uint4*)(ap_ + 4);
      uint4 hi4, lo4;
      hi4.x = rne_hi2(f0.x, f0.y); lo4.x = rne_lo2(f0.x, f0.y);
      hi4.y = rne_hi2(f0.z, f0.w); lo4.y = rne_lo2(f0.z, f0.w);
      hi4.z = rne_hi2(f1.x, f1.y); lo4.z = rne_lo2(f1.x, f1.y);
      hi4.w = rne_hi2(f1.z, f1.w); lo4.w = rne_lo2(f1.z, f1.w);
      *(uint4*)(&At[0][r * 40 + c8]) = hi4;
      *(uint4*)(&At[1][r * 40 + c8]) = lo4;
      *(uint4*)(&Bt[0][r * 40 + c8]) =
          *(const uint4*)(&Bhi[(size_t)(col0 + r) * K + k0 + c8]);
      *(uint4*)(&Bt[1][r * 40 + c8]) =
          *(const uint4*)(&Blo[(size_t)(col0 + r) * K + k0 + c8]);
    }
    __syncthreads();
    short8 ah[4], al[4], bh[4], bl[4];
    const int koff = quad * 8;
#pragma unroll
    for (int i = 0; i < 4; ++i) {
      ah[i] = *(const short8*)(&At[0][(wm + i * 16 + l15) * 40 + koff]);
      al[i] = *(const short8*)(&At[1][(wm + i * 16 + l15) * 40 + koff]);
      bh[i] = *(const short8*)(&Bt[0][(wn + i * 16 + l15) * 40 + koff]);
      bl[i] = *(const short8*)(&Bt[1][(wn + i * 16 + l15) * 40 + koff]);
    }
#pragma unroll
    for (int i = 0; i < 4; ++i)
#pragma unroll
      for (int j = 0; j < 4; ++j) {
        acc[i][j] = __builtin_amdgcn_mfma_f32_16x16x32_bf16(ah[i], bh[j], acc[i][j], 0, 0, 0);
        acc[i][j] = __builtin_amdgcn_mfma_f32_16x16x32_bf16(ah[i], bl[j], acc[i][j], 0, 0, 0);
        acc[i][j] = __builtin_amdgcn_mfma_f32_16x16x32_bf16(al[i], bh[j], acc[i][j], 0, 0, 0);
      }
    __syncthreads();
  }
#pragma unroll
  for (int j = 0; j < 4; ++j) {
    const int col = col0 + wn + j * 16 + l15;
    const float bv = bias ? bias[col] : 0.f;
#pragma unroll
    for (int i = 0; i < 4; ++i) {
#pragma unroll
      for (int r = 0; r < 4; ++r) {
        int row = row0 + wm + i * 16 + quad * 4 + r;
        C[(size_t)row * N + col] = acc[i][j][r] + bv;
      }
    }
  }
}

// ---------------------------------------------------------------- MFMA GEMM, spike-A 2-term
__global__ __launch_bounds__(256) void k_gemm_spike2(
    const float* __restrict__ A, const ushort_t* __restrict__ Bhi,
    const ushort_t* __restrict__ Blo, const float* __restrict__ bias,
    float* __restrict__ C, int M, int N, int K) {
  __shared__ ushort_t At[128 * 72];
  __shared__ ushort_t Bt[2][128 * 72];
  const int tid = threadIdx.x;
  const int row0 = blockIdx.x * 128, col0 = blockIdx.y * 128;
  const int w = tid >> 6, lane = tid & 63;
  const int wm = (w >> 1) * 64, wn = (w & 1) * 64;
  const int l15 = lane & 15, quad = lane >> 4;
  float4v acc[4][4];
#pragma unroll
  for (int i = 0; i < 4; ++i)
#pragma unroll
    for (int j = 0; j < 4; ++j) acc[i][j] = (float4v){0.f, 0.f, 0.f, 0.f};

  for (int k0 = 0; k0 < K; k0 += 64) {
#pragma unroll
    for (int it = 0; it < 4; ++it) {
      int idx = it * 256 + tid;          // 0..1023
      int r = idx >> 3;                  // row 0..127
      int c8 = (idx & 7) << 3;           // k-offset 0..56 step 8
      uint4 pa = *(const uint4*)(&A[(size_t)(row0 + r) * K + k0 + c8]);
      uint4 pb = *(const uint4*)(&A[(size_t)(row0 + r) * K + k0 + c8 + 4]);
      uint4 st;
      st.x = (pa.x >> 16) | (pa.y & 0xFFFF0000u);
      st.y = (pa.z >> 16) | (pa.w & 0xFFFF0000u);
      st.z = (pb.x >> 16) | (pb.y & 0xFFFF0000u);
      st.w = (pb.z >> 16) | (pb.w & 0xFFFF0000u);
      *(uint4*)(&At[r * 72 + c8]) = st;
      *(uint4*)(&Bt[0][r * 72 + c8]) =
          *(const uint4*)(&Bhi[(size_t)(col0 + r) * K + k0 + c8]);
      *(uint4*)(&Bt[1][r * 72 + c8]) =
          *(const uint4*)(&Blo[(size_t)(col0 + r) * K + k0 + c8]);
    }
    __syncthreads();
#pragma unroll
    for (int ks = 0; ks < 2; ++ks) {
      short8 a[4], bh[4], bl[4];
      const int koff = ks * 32 + quad * 8;
#pragma unroll
      for (int i = 0; i < 4; ++i) {
        a[i] = *(const short8*)(&At[(wm + i * 16 + l15) * 72 + koff]);
        bh[i] = *(const short8*)(&Bt[0][(wn + i * 16 + l15) * 72 + koff]);
        bl[i] = *(const short8*)(&Bt[1][(wn + i * 16 + l15) * 72 + koff]);
      }
#pragma unroll
      for (int i = 0; i < 4; ++i)
#pragma unroll
        for (int j = 0; j < 4; ++j) {
          acc[i][j] = __builtin_amdgcn_mfma_f32_16x16x32_bf16(a[i], bh[j], acc[i][j], 0, 0, 0);
          acc[i][j] = __builtin_amdgcn_mfma_f32_16x16x32_bf16(a[i], bl[j], acc[i][j], 0, 0, 0);
        }
    }
    __syncthreads();
  }
#pragma unroll
  for (int j = 0; j < 4; ++j) {
    const int col = col0 + wn + j * 16 + l15;
    const float bv = bias ? bias[col] : 0.f;
#pragma unroll
    for (int i = 0; i < 4; ++i) {
#pragma unroll
      for (int r = 0; r < 4; ++r) {
        int row = row0 + wm + i * 16 + quad * 4 + r;
        C[(size_t)row * N + col] = acc[i][j][r] + bv;
      }
    }
  }
}

// ---------------------------------------------------------------- LIF scan #1
__global__ __launch_bounds__(256) void k_lif1(float* __restrict__ p) {
  const int id = blockIdx.x * 256 + threadIdx.x;  // 0..32767
  const size_t base = (size_t)(id >> 9) * (T_STEPS * HID) + (id & 511);
  float mem = 0.f;
  for (int t0 = 0; t0 < T_STEPS; t0 += 8) {
    float v[8];
#pragma unroll
    for (int j = 0; j < 8; ++j) v[j] = p[base + (size_t)(t0 + j) * HID];
#pragma unroll
    for (int j = 0; j < 8; ++j) {
      float nm = BETA * mem + v[j];
      float sp = nm > THR ? 1.0f : 0.0f;
      p[base + (size_t)(t0 + j) * HID] = sp;
      mem = nm - sp;
    }
  }
}

// ---------------------------------------------------------------- recurrent scan (R13 == R10)
// R10-exact: qword-pair P exchange, 448-lane 8B compiler-managed agent-scope
// atomic polls, full-drain __syncthreads, parity dbuf memLDS, in-wave
// swizzle reduce, membranes in registers on lif lanes.
__global__ __launch_bounds__(512) void k_recurrent_cp(
    const float* __restrict__ W, const float* __restrict__ b_hh,
    float* __restrict__ rp, float* __restrict__ P) {
  const int tid = threadIdx.x;
  const int grp = blockIdx.x & 31;  // stride-32 members: same XCD under %8 RR
  const int j   = blockIdx.x >> 5;  // output-column block 0..7
  const int w   = tid >> 6;         // wave 0..7
  const int l   = tid & 63;
  const int q   = l >> 3;           // row-in-group 0..7
  const int c   = l & 7;            // k-chunk of this lane
  const int row = (w << 3) + q;     // 0..63 output row within block
  const int g0  = j << 6;

  __shared__ float memLDS[2][2][8 * 72];  // [parity][ob][chunk*72 + k]

  for (int i = tid; i < 2 * 2 * 8 * 72; i += 512) ((float*)memLDS)[i] = 0.f;

  float Wreg[64];
  {
    const float* wrow = W + (size_t)(g0 + row) * HID + (c << 6);
#pragma unroll
    for (int k4 = 0; k4 < 16; ++k4) {
      float4 w4 = *(const float4*)(wrow + 4 * k4);
      Wreg[4 * k4 + 0] = w4.x; Wreg[4 * k4 + 1] = w4.y;
      Wreg[4 * k4 + 2] = w4.z; Wreg[4 * k4 + 3] = w4.w;
    }
  }

  const bool lif = (c == 0);
  const int og = g0 + row;
  const size_t rp_b0 = (size_t)(grp * 2 + 0) * (T_STEPS * HID) + og;
  const size_t rp_b1 = (size_t)(grp * 2 + 1) * (T_STEPS * HID) + og;
  const float bhh_v = lif ? b_hh[og] : 0.f;
  float mem0 = 0.f, mem1 = 0.f;     // membrane registers (valid on lif lanes)

  const int rg = (tid < g0) ? tid : tid + 64;        // remote row (tid<448)
  const int raddr = (rg >> 6) * 72 + (rg & 63);

  u64_t* Pq = (u64_t*)P;

  __syncthreads();

  for (int t = 0; t < T_STEPS; ++t) {
    const int par = t & 1;
    float ip0 = 0.f, ip1 = 0.f;
    if (lif) {
      ip0 = rp[rp_b0 + (size_t)t * HID];
      ip1 = rp[rp_b1 + (size_t)t * HID];
    }
    if (t > 0 && tid < 448) {
      const u64_t* ap = Pq + ((size_t)(t - 1) * 32 + grp) * 512 + rg;
      u64_t u = __hip_atomic_load(ap, __ATOMIC_RELAXED, __HIP_MEMORY_SCOPE_AGENT);
      int tries = 0;
      while (((uint32_t)u == SENT) || ((uint32_t)(u >> 32) == SENT)) {
        if (++tries > 24) __builtin_amdgcn_s_sleep(1);
        u = __hip_atomic_load(ap, __ATOMIC_RELAXED, __HIP_MEMORY_SCOPE_AGENT);
      }
      memLDS[par][0][raddr] = __uint_as_float((uint32_t)u);
      memLDS[par][1][raddr] = __uint_as_float((uint32_t)(u >> 32));
    }
    __syncthreads();

    float p0a = 0.f, p0b = 0.f, p1a = 0.f, p1b = 0.f;
    {
      const float4* m0 = (const float4*)&memLDS[par][0][c * 72];
      const float4* m1 = (const float4*)&memLDS[par][1][c * 72];
#pragma unroll
      for (int k4 = 0; k4 < 16; ++k4) {
        float4 a = m0[k4];
        float4 b = m1[k4];
        p0a = fmaf(Wreg[4 * k4 + 0], a.x, p0a);
        p0b = fmaf(Wreg[4 * k4 + 1], a.y, p0b);
        p0a = fmaf(Wreg[4 * k4 + 2], a.z, p0a);
        p0b = fmaf(Wreg[4 * k4 + 3], a.w, p0b);
        p1a = fmaf(Wreg[4 * k4 + 0], b.x, p1a);
        p1b = fmaf(Wreg[4 * k4 + 1], b.y, p1b);
        p1a = fmaf(Wreg[4 * k4 + 2], b.z, p1a);
        p1b = fmaf(Wreg[4 * k4 + 3], b.w, p1b);
      }
    }
    const int i0 = __float_as_int(p0a + p0b);
    const int i1 = __float_as_int(p1a + p1b);
    // serial ascending-chunk reduce across lanes (l&56)+ss  (== old scratch)
    float s0 = 0.f, s1 = 0.f;
#define RED(ss)                                                                 \
    s0 += __int_as_float(__builtin_amdgcn_ds_swizzle(i0, ((ss) << 5) | 0x18)); \
    s1 += __int_as_float(__builtin_amdgcn_ds_swizzle(i1, ((ss) << 5) | 0x18));
    RED(0) RED(1) RED(2) RED(3) RED(4) RED(5) RED(6) RED(7)
#undef RED

    if (lif) {
      const int npar = par ^ 1;
      const float nm0 = BETA * mem0 + ip0 + s0 + bhh_v;
      const float sp0 = nm0 > THR ? 1.0f : 0.0f;
      mem0 = nm0 - sp0;
      const float nm1 = BETA * mem1 + ip1 + s1 + bhh_v;
      const float sp1 = nm1 > THR ? 1.0f : 0.0f;
      mem1 = nm1 - sp1;
      const u64_t pk =
          ((u64_t)__float_as_uint(mem1) << 32) | (u64_t)__float_as_uint(mem0);
      __hip_atomic_store(Pq + ((size_t)t * 32 + grp) * 512 + og, pk,
                         __ATOMIC_RELAXED, __HIP_MEMORY_SCOPE_AGENT);
      rp[rp_b0 + (size_t)t * HID] = sp0;
      rp[rp_b1 + (size_t)t * HID] = sp1;
      memLDS[npar][0][j * 72 + row] = mem0;
      memLDS[npar][1][j * 72 + row] = mem1;
    }
  }
}

// ---------------------------------------------------------------- attend + threshold
__global__ __launch_bounds__(256) void k_attend(
    const float* __restrict__ op, const float* __restrict__ attn,
    const float* __restrict__ b_out, float* __restrict__ out) {
  const int b = blockIdx.x;
  const int o = threadIdx.x;
  float s = b_out[o];
  const float* opb = op + (size_t)b * T_STEPS * OUT_DIM + o;
  for (int t0 = 0; t0 < T_STEPS; t0 += 8) {
    float av[8], pv[8];
#pragma unroll
    for (int j = 0; j < 8; ++j) {
      av[j] = attn[(size_t)(t0 + j) * OUT_DIM + o];
      pv[j] = opb[(size_t)(t0 + j) * OUT_DIM];
    }
#pragma unroll
    for (int j = 0; j < 8; ++j) s = fmaf(av[j], pv[j], s);
  }
  out[b * OUT_DIM + o] = s > THR ? 1.0f : 0.0f;
}

// ---------------------------------------------------------------- launch
extern "C" void kernel_launch(void* const* d_in, const int* in_sizes, int n_in,
                              void* d_out, int out_size, void* d_ws, size_t ws_size,
                              hipStream_t stream) {
  (void)in_sizes; (void)n_in; (void)out_size; (void)ws_size;
  const float* x     = (const float*)d_in[0];
  const float* W_in  = (const float*)d_in[1];
  const float* b_in  = (const float*)d_in[2];
  const float* W_ih  = (const float*)d_in[3];
  const float* b_ih  = (const float*)d_in[4];
  const float* W_hh  = (const float*)d_in[5];
  const float* b_hh  = (const float*)d_in[6];
  const float* W_out = (const float*)d_in[7];
  const float* b_out = (const float*)d_in[8];
  const float* TA    = (const float*)d_in[9];

  float* ws = (float*)d_ws;
  float* proj  = ws;                           // 16.78M floats: GEMM1 out / P / out_proj
  float* rproj = proj + (size_t)32768 * 512;   // 16.78M floats: GEMM2 out
  float* attn  = rproj + (size_t)32768 * 512;  // 131072 floats
  ushort_t* wih_hi = (ushort_t*)(attn + 512 * 256);
  ushort_t* wih_lo = wih_hi + 512 * 512;
  ushort_t* win_hi = wih_lo + 512 * 512;
  ushort_t* win_lo = win_hi + 512 * 256;
  ushort_t* wout_hi = win_lo + 512 * 256;
  ushort_t* wout_lo = wout_hi + 256 * 512;
  float* P = proj;            // exchange slots [t][grp][row] qword pairs
  float* out_proj = proj;     // (b*T, O) fp32, written after recurrent

  k_softmax_t<<<8, 256, 0, stream>>>(TA, attn);
  k_split3w<<<512, 256, 0, stream>>>(W_in, win_hi, win_lo,
                                     W_ih, wih_hi, wih_lo,
                                     W_out, wout_hi, wout_lo);

  // GEMM1: proj = x @ W_in^T + b_in   (M=32768, N=512, K=256), x split fused
  k_gemm_fsplit3<<<dim3(256, 4), 256, 0, stream>>>(
      x, win_hi, win_lo, b_in, proj, 32768, 512, 256);
  k_lif1<<<128, 256, 0, stream>>>(proj);
  // GEMM2: rproj = spikes @ W_ih^T + b_ih   (M=32768, N=512, K=512)
  k_gemm_spike2<<<dim3(256, 4), 256, 0, stream>>>(
      proj, wih_hi, wih_lo, b_ih, rproj, 32768, 512, 512);
  k_fill_nan<<<256, 256, 0, stream>>>((uint32_t*)P);  // proj dead after GEMM2
  k_recurrent_cp<<<256, 512, 0, stream>>>(W_hh, b_hh, rproj, P);
  // GEMM3: out_proj = tspikes @ W_out^T   (M=32768, N=256, K=512, no bias)
  k_gemm_spike2<<<dim3(256, 2), 256, 0, stream>>>(
      rproj, wout_hi, wout_lo, nullptr, out_proj, 32768, 256, 512);
  k_attend<<<64, 256, 0, stream>>>(out_proj, attn, b_out, (float*)d_out);
}